// Round 1
// baseline (539.870 us; speedup 1.0000x reference)
//
#include <hip/hip_runtime.h>
#include <hip/hip_bf16.h>

// TransformerBlockQuantum on MI355X — bf16 MFMA pipeline, fp32 accumulate.
// B=4 S=2048 E=1024 H=16 Dk=64 F=4096 Q=8.

typedef __attribute__((ext_vector_type(8))) short bf16x8;
typedef __attribute__((ext_vector_type(4))) float f32x4;
typedef __attribute__((ext_vector_type(4))) unsigned short u16x4;

__device__ __forceinline__ unsigned short f2bf(float f) {
  union { float f; unsigned int u; } v; v.f = f;
  return (unsigned short)((v.u + 0x7FFFu + ((v.u >> 16) & 1u)) >> 16);
}
__device__ __forceinline__ float bf2f(unsigned short h) {
  union { unsigned int u; float f; } v; v.u = ((unsigned int)h) << 16;
  return v.f;
}
__device__ __forceinline__ f32x4 mfma16(bf16x8 a, bf16x8 b, f32x4 c) {
  return __builtin_amdgcn_mfma_f32_16x16x32_bf16(a, b, c, 0, 0, 0);
}

// ---------------- cast x (f32 -> bf16), 4 elems/thread ----------------
__global__ __launch_bounds__(256) void cast_x_kernel(const float* __restrict__ in,
                                                     unsigned short* __restrict__ out,
                                                     int n4) {
  int i = blockIdx.x * 256 + threadIdx.x;
  if (i >= n4) return;
  float4 v = ((const float4*)in)[i];
  u16x4 o = { f2bf(v.x), f2bf(v.y), f2bf(v.z), f2bf(v.w) };
  ((u16x4*)out)[i] = o;
}

// ------------- transpose + cast: in[K][N] f32 -> out[N][K] bf16 -------------
__global__ __launch_bounds__(256) void transpose_cast_kernel(const float* __restrict__ in,
                                                             unsigned short* __restrict__ out,
                                                             int K, int N) {
  __shared__ float tile[32][33];
  const int n0 = blockIdx.x * 32, k0 = blockIdx.y * 32;
  const int tx = threadIdx.x, ty = threadIdx.y;  // block (32,8)
#pragma unroll
  for (int i = 0; i < 32; i += 8)
    tile[ty + i][tx] = in[(long)(k0 + ty + i) * N + n0 + tx];
  __syncthreads();
#pragma unroll
  for (int i = 0; i < 32; i += 8)
    out[(long)(n0 + ty + i) * K + k0 + tx] = f2bf(tile[tx][ty + i]);
}

// ---------------- GEMM: C[M,N] = A[M,K](bf16) @ BT[N,K](bf16)^T ----------------
// 128x128 tile, 4 waves (2x2), each wave 64x64 = 4x4 frags of 16x16x32 MFMA.
// EPI: 0 = store f32, 1 = store bf16.
template<int EPI>
__global__ __launch_bounds__(256) void gemm_bt(const unsigned short* __restrict__ A,
                                               const unsigned short* __restrict__ BT,
                                               void* __restrict__ Cv,
                                               int M, int N, int K) {
  __shared__ __align__(16) unsigned short lsA[128][40];
  __shared__ __align__(16) unsigned short lsB[128][40];
  const int tid = threadIdx.x;
  const int l   = tid & 63;
  const int wv  = tid >> 6;
  const int wr  = wv >> 1, wc = wv & 1;
  const int l16 = l & 15, lhi = l >> 4;
  const long m0 = (long)blockIdx.y * 128, n0 = (long)blockIdx.x * 128;

  const int srow = tid >> 2;
  const int sk   = (tid & 3) * 8;
  const unsigned short* pA = A + (m0 + srow) * (long)K + sk;
  const unsigned short* pB = BT + (n0 + srow) * (long)K + sk;
  const long rstep = 64L * K;

  f32x4 acc[4][4];
#pragma unroll
  for (int m = 0; m < 4; m++)
#pragma unroll
    for (int n = 0; n < 4; n++) acc[m][n] = (f32x4){0.f, 0.f, 0.f, 0.f};

  bf16x8 pa0 = *(const bf16x8*)(pA);
  bf16x8 pa1 = *(const bf16x8*)(pA + rstep);
  bf16x8 pb0 = *(const bf16x8*)(pB);
  bf16x8 pb1 = *(const bf16x8*)(pB + rstep);

  for (int ks = 0; ks < K; ks += 32) {
    __syncthreads();
    *(bf16x8*)&lsA[srow][sk]      = pa0;
    *(bf16x8*)&lsA[srow + 64][sk] = pa1;
    *(bf16x8*)&lsB[srow][sk]      = pb0;
    *(bf16x8*)&lsB[srow + 64][sk] = pb1;
    __syncthreads();
    const int kn = ks + 32;
    if (kn < K) {  // prefetch next tile into regs; overlaps with MFMA below
      pa0 = *(const bf16x8*)(pA + kn);
      pa1 = *(const bf16x8*)(pA + rstep + kn);
      pb0 = *(const bf16x8*)(pB + kn);
      pb1 = *(const bf16x8*)(pB + rstep + kn);
    }
    bf16x8 af[4], bfr[4];
#pragma unroll
    for (int m = 0; m < 4; m++) af[m]  = *(const bf16x8*)&lsA[wr * 64 + m * 16 + l16][lhi * 8];
#pragma unroll
    for (int n = 0; n < 4; n++) bfr[n] = *(const bf16x8*)&lsB[wc * 64 + n * 16 + l16][lhi * 8];
#pragma unroll
    for (int m = 0; m < 4; m++)
#pragma unroll
      for (int n = 0; n < 4; n++)
        acc[m][n] = mfma16(af[m], bfr[n], acc[m][n]);
  }

  const long crow = m0 + wr * 64;
  const long ccol = n0 + wc * 64;
  if (EPI == 0) {
    float* C = (float*)Cv;
#pragma unroll
    for (int m = 0; m < 4; m++)
#pragma unroll
      for (int n = 0; n < 4; n++) {
        const long r0 = crow + m * 16 + lhi * 4;
        const long c0 = ccol + n * 16 + l16;
#pragma unroll
        for (int r = 0; r < 4; r++) C[(r0 + r) * (long)N + c0] = acc[m][n][r];
      }
  } else {
    unsigned short* C = (unsigned short*)Cv;
#pragma unroll
    for (int m = 0; m < 4; m++)
#pragma unroll
      for (int n = 0; n < 4; n++) {
        const long r0 = crow + m * 16 + lhi * 4;
        const long c0 = ccol + n * 16 + l16;
#pragma unroll
        for (int r = 0; r < 4; r++) C[(r0 + r) * (long)N + c0] = f2bf(acc[m][n][r]);
      }
  }
}

// ---------------- flash attention ----------------
// qkv: [8192][3072] bf16 (q | k | v each 1024 wide, head h at h*64).
// grid: (S/64, B*H). block 256 = 4 waves; wave w owns 16 q-rows.
__global__ __launch_bounds__(256) void attn_kernel(const unsigned short* __restrict__ qkv,
                                                   unsigned short* __restrict__ ctx) {
  __shared__ __align__(16) unsigned short lsK[64][72];      // [t][d]
  __shared__ __align__(16) unsigned short lsV[64][72];      // [d][t] (transposed)
  __shared__ __align__(16) unsigned short lsP[4][16][72];   // per-wave P strip

  const int tid = threadIdx.x;
  const int l = tid & 63, w = tid >> 6;
  const int l16 = l & 15, lhi = l >> 4;
  const int s0 = blockIdx.x * 64;
  const int bh = blockIdx.y;
  const int b = bh >> 4, h = bh & 15;

  // Q fragments (rows s0 + w*16 + l16), scale by 1/sqrt(64)=0.125 (exact pow2)
  const unsigned short* qp = qkv + ((long)(b * 2048 + s0 + w * 16 + l16)) * 3072 + h * 64;
  bf16x8 qa[2];
#pragma unroll
  for (int kc = 0; kc < 2; kc++) {
    bf16x8 t = *(const bf16x8*)(qp + kc * 32 + lhi * 8);
#pragma unroll
    for (int j = 0; j < 8; j++) t[j] = (short)f2bf(bf2f((unsigned short)t[j]) * 0.125f);
    qa[kc] = t;
  }

  f32x4 oacc[4];
#pragma unroll
  for (int n = 0; n < 4; n++) oacc[n] = (f32x4){0.f, 0.f, 0.f, 0.f};
  float mi[4] = {-1e30f, -1e30f, -1e30f, -1e30f};
  float li[4] = {0.f, 0.f, 0.f, 0.f};

  const int tr = tid >> 2;            // 0..63 key row within tile
  const int dd = (tid & 3) * 16;      // 16 d-elements per thread
  const unsigned short* kbase = qkv + (long)(b * 2048) * 3072 + 1024 + h * 64;
  const unsigned short* vbase = qkv + (long)(b * 2048) * 3072 + 2048 + h * 64;

  bf16x8 k0 = *(const bf16x8*)(kbase + (long)tr * 3072 + dd);
  bf16x8 k1 = *(const bf16x8*)(kbase + (long)tr * 3072 + dd + 8);
  bf16x8 v0 = *(const bf16x8*)(vbase + (long)tr * 3072 + dd);
  bf16x8 v1 = *(const bf16x8*)(vbase + (long)tr * 3072 + dd + 8);

  for (int t0 = 0; t0 < 2048; t0 += 64) {
    __syncthreads();
    *(bf16x8*)&lsK[tr][dd]     = k0;
    *(bf16x8*)&lsK[tr][dd + 8] = k1;
#pragma unroll
    for (int j = 0; j < 8; j++) {
      lsV[dd + j][tr]     = (unsigned short)v0[j];
      lsV[dd + 8 + j][tr] = (unsigned short)v1[j];
    }
    __syncthreads();
    if (t0 + 64 < 2048) {  // prefetch next K/V tile
      k0 = *(const bf16x8*)(kbase + (long)(t0 + 64 + tr) * 3072 + dd);
      k1 = *(const bf16x8*)(kbase + (long)(t0 + 64 + tr) * 3072 + dd + 8);
      v0 = *(const bf16x8*)(vbase + (long)(t0 + 64 + tr) * 3072 + dd);
      v1 = *(const bf16x8*)(vbase + (long)(t0 + 64 + tr) * 3072 + dd + 8);
    }

    // S = (Q*0.125) K^T : 4 t-frags x 2 k-chunks
    f32x4 sa[4];
#pragma unroll
    for (int n = 0; n < 4; n++) {
      f32x4 z = (f32x4){0.f, 0.f, 0.f, 0.f};
      bf16x8 kb0 = *(const bf16x8*)&lsK[n * 16 + l16][lhi * 8];
      bf16x8 kb1 = *(const bf16x8*)&lsK[n * 16 + l16][32 + lhi * 8];
      z = mfma16(qa[0], kb0, z);
      z = mfma16(qa[1], kb1, z);
      sa[n] = z;
    }

    // online softmax (row = lhi*4 + r; reduce over 16 lanes sharing lhi)
    float sc[4];
#pragma unroll
    for (int r = 0; r < 4; r++) {
      float vm = fmaxf(fmaxf(sa[0][r], sa[1][r]), fmaxf(sa[2][r], sa[3][r]));
      vm = fmaxf(vm, __shfl_xor(vm, 1));
      vm = fmaxf(vm, __shfl_xor(vm, 2));
      vm = fmaxf(vm, __shfl_xor(vm, 4));
      vm = fmaxf(vm, __shfl_xor(vm, 8));
      const float mnew = fmaxf(mi[r], vm);
      sc[r] = __expf(mi[r] - mnew);
      float rs = 0.f;
#pragma unroll
      for (int n = 0; n < 4; n++) {
        float p = __expf(sa[n][r] - mnew);
        sa[n][r] = p;
        rs += p;
      }
      rs += __shfl_xor(rs, 1);
      rs += __shfl_xor(rs, 2);
      rs += __shfl_xor(rs, 4);
      rs += __shfl_xor(rs, 8);
      li[r] = li[r] * sc[r] + rs;
      mi[r] = mnew;
    }
#pragma unroll
    for (int n = 0; n < 4; n++)
#pragma unroll
      for (int r = 0; r < 4; r++) oacc[n][r] *= sc[r];

    // P (C-layout) -> LDS strip -> A-fragments
#pragma unroll
    for (int n = 0; n < 4; n++)
#pragma unroll
      for (int r = 0; r < 4; r++)
        lsP[w][lhi * 4 + r][n * 16 + l16] = f2bf(sa[n][r]);
    __syncthreads();

    bf16x8 pa0 = *(const bf16x8*)&lsP[w][l16][lhi * 8];
    bf16x8 pa1 = *(const bf16x8*)&lsP[w][l16][32 + lhi * 8];
#pragma unroll
    for (int n = 0; n < 4; n++) {
      bf16x8 vb0 = *(const bf16x8*)&lsV[n * 16 + l16][lhi * 8];
      bf16x8 vb1 = *(const bf16x8*)&lsV[n * 16 + l16][32 + lhi * 8];
      oacc[n] = mfma16(pa0, vb0, oacc[n]);
      oacc[n] = mfma16(pa1, vb1, oacc[n]);
    }
  }

  float inv[4];
#pragma unroll
  for (int r = 0; r < 4; r++) inv[r] = 1.f / li[r];
  const long orow = (long)(b * 2048 + s0 + w * 16 + lhi * 4);
#pragma unroll
  for (int n = 0; n < 4; n++)
#pragma unroll
    for (int r = 0; r < 4; r++)
      ctx[(orow + r) * 1024 + h * 64 + n * 16 + l16] = f2bf(oacc[n][r] * inv[r]);
}

// ---------------- LayerNorm(ra + rb) * g + b; optional quantum feature out ----------------
template<bool QO>
__global__ __launch_bounds__(256) void ln_kernel(const float* __restrict__ ra,
                                                 const float* __restrict__ rb,
                                                 const float* __restrict__ g,
                                                 const float* __restrict__ bb,
                                                 float* __restrict__ out,
                                                 float* __restrict__ qo,
                                                 const float* __restrict__ theta) {
  const int row = blockIdx.x;
  const int tid = threadIdx.x;
  const long base = (long)row * 1024 + tid * 4;
  float4 a = *(const float4*)(ra + base);
  float4 bv = *(const float4*)(rb + base);
  float4 r;
  r.x = a.x + bv.x; r.y = a.y + bv.y; r.z = a.z + bv.z; r.w = a.w + bv.w;
  float s  = r.x + r.y + r.z + r.w;
  float ss = r.x * r.x + r.y * r.y + r.z * r.z + r.w * r.w;
  for (int off = 32; off; off >>= 1) {
    s  += __shfl_down(s, off);
    ss += __shfl_down(ss, off);
  }
  __shared__ float red[4][2];
  const int wv = tid >> 6;
  if ((tid & 63) == 0) { red[wv][0] = s; red[wv][1] = ss; }
  __syncthreads();
  s  = red[0][0] + red[1][0] + red[2][0] + red[3][0];
  ss = red[0][1] + red[1][1] + red[2][1] + red[3][1];
  const float mu  = s * (1.f / 1024.f);
  const float var = ss * (1.f / 1024.f) - mu * mu;
  const float rsv = rsqrtf(var + 1e-5f);
  float4 gv  = *(const float4*)(g + tid * 4);
  float4 bbv = *(const float4*)(bb + tid * 4);
  float4 y;
  y.x = (r.x - mu) * rsv * gv.x + bbv.x;
  y.y = (r.y - mu) * rsv * gv.y + bbv.y;
  y.z = (r.z - mu) * rsv * gv.z + bbv.z;
  y.w = (r.w - mu) * rsv * gv.w + bbv.w;
  *(float4*)(out + base) = y;
  if constexpr (QO) {
    if (tid < 2) {
      float yv[4] = {y.x, y.y, y.z, y.w};
#pragma unroll
      for (int c = 0; c < 4; c++)
        qo[(long)row * 8 + tid * 4 + c] = __cosf(2.f * yv[c] + theta[tid * 4 + c]);
    }
  }
}

// ---------------- h = relu(qo @ w1) -> bf16 [8192][4096], 4 f per thread ----------------
__global__ __launch_bounds__(256) void ffn_a_kernel(const float* __restrict__ qo,
                                                    const float* __restrict__ w1,
                                                    unsigned short* __restrict__ h) {
  const long idx = (long)blockIdx.x * 256 + threadIdx.x;
  const int row = (int)(idx >> 10);
  const int f   = (int)(idx & 1023) << 2;
  const float4 q01 = *(const float4*)(qo + (long)row * 8);
  const float4 q23 = *(const float4*)(qo + (long)row * 8 + 4);
  const float qv[8] = {q01.x, q01.y, q01.z, q01.w, q23.x, q23.y, q23.z, q23.w};
  float a0 = 0.f, a1 = 0.f, a2 = 0.f, a3 = 0.f;
#pragma unroll
  for (int q = 0; q < 8; q++) {
    float4 wv4 = *(const float4*)(w1 + q * 4096 + f);
    a0 += qv[q] * wv4.x;
    a1 += qv[q] * wv4.y;
    a2 += qv[q] * wv4.z;
    a3 += qv[q] * wv4.w;
  }
  u16x4 o = { f2bf(fmaxf(a0, 0.f)), f2bf(fmaxf(a1, 0.f)),
              f2bf(fmaxf(a2, 0.f)), f2bf(fmaxf(a3, 0.f)) };
  *(u16x4*)(h + (long)row * 4096 + f) = o;
}

extern "C" void kernel_launch(void* const* d_in, const int* in_sizes, int n_in,
                              void* d_out, int out_size, void* d_ws, size_t ws_size,
                              hipStream_t stream) {
  const float* x     = (const float*)d_in[0];
  const float* wq    = (const float*)d_in[1];
  const float* wk    = (const float*)d_in[2];
  const float* wv    = (const float*)d_in[3];
  const float* wo    = (const float*)d_in[4];
  const float* theta = (const float*)d_in[5];
  const float* w1    = (const float*)d_in[6];
  const float* w2    = (const float*)d_in[7];
  const float* g1    = (const float*)d_in[8];
  const float* b1    = (const float*)d_in[9];
  const float* g2    = (const float*)d_in[10];
  const float* b2    = (const float*)d_in[11];
  float* out = (float*)d_out;
  char* ws = (char*)d_ws;

  const long MB = 1 << 20;
  unsigned short* xb    = (unsigned short*)(ws);             // 16 MB; reused as ctx
  unsigned short* wqkvT = (unsigned short*)(ws + 16 * MB);   // 6 MB
  unsigned short* woT   = (unsigned short*)(ws + 22 * MB);   // 2 MB
  unsigned short* w2T   = (unsigned short*)(ws + 24 * MB);   // 8 MB
  float*          x1    = (float*)(ws + 32 * MB);            // 32 MB
  float*          fbuf  = (float*)(ws + 64 * MB);            // 32 MB (attn_out, then ffn_out)
  unsigned short* qkv   = (unsigned short*)(ws + 96 * MB);   // 48 MB; reused as h (64 MB)
  float*          qo    = (float*)(ws + 160 * MB);           // 256 KB
  unsigned short* ctx   = xb;
  unsigned short* hbuf  = qkv;

  // prep: casts + weight transposes
  cast_x_kernel<<<8192, 256, 0, stream>>>(x, xb, 8192 * 1024 / 4);
  dim3 tb(32, 8);
  transpose_cast_kernel<<<dim3(32, 32), tb, 0, stream>>>(wq, wqkvT, 1024, 1024);
  transpose_cast_kernel<<<dim3(32, 32), tb, 0, stream>>>(wk, wqkvT + 1024 * 1024, 1024, 1024);
  transpose_cast_kernel<<<dim3(32, 32), tb, 0, stream>>>(wv, wqkvT + 2048 * 1024, 1024, 1024);
  transpose_cast_kernel<<<dim3(32, 32), tb, 0, stream>>>(wo, woT, 1024, 1024);
  transpose_cast_kernel<<<dim3(32, 128), tb, 0, stream>>>(w2, w2T, 4096, 1024);

  // qkv = x @ [wq|wk|wv]  (M=8192, N=3072, K=1024) -> bf16
  gemm_bt<1><<<dim3(24, 64), 256, 0, stream>>>(xb, wqkvT, qkv, 8192, 3072, 1024);

  // flash attention -> ctx bf16 [8192][1024]
  attn_kernel<<<dim3(32, 64), 256, 0, stream>>>(qkv, ctx);

  // attn_out = ctx @ wo -> f32
  gemm_bt<0><<<dim3(8, 64), 256, 0, stream>>>(ctx, woT, fbuf, 8192, 1024, 1024);

  // x1 = LN(x + attn_out); qo = cos(2*x1[:, :8] + theta)
  ln_kernel<true><<<8192, 256, 0, stream>>>(x, fbuf, g1, b1, x1, qo, theta);

  // h = relu(qo @ w1) -> bf16
  ffn_a_kernel<<<32768, 256, 0, stream>>>(qo, w1, hbuf);

  // ffn_out = h @ w2 -> f32
  gemm_bt<0><<<dim3(8, 64), 256, 0, stream>>>(hbuf, w2T, fbuf, 8192, 1024, 4096);

  // out = LN(x1 + ffn_out)
  ln_kernel<false><<<8192, 256, 0, stream>>>(x1, fbuf, g2, b2, out, nullptr, nullptr);
}